// Round 1
// baseline (827.751 us; speedup 1.0000x reference)
//
#include <hip/hip_runtime.h>
#include <math.h>

#define BB 64
#define SS 2048
#define HH 1024
#define LL 15

// ---------------- span-mean + tanh ----------------
// grid: 64 blocks (one per batch), 256 threads
// t_cat[b, 0:H]   = tanh(x[b,0,:])
// t_cat[b, H:2H]  = tanh(mean(x[b, s1:e1, :]))
// t_cat[b, 2H:3H] = tanh(mean(x[b, s2:e2, :]))
__global__ void span_tanh_kernel(const float* __restrict__ x,
                                 const int* __restrict__ eidx,
                                 float* __restrict__ t_cat) {
  int b = blockIdx.x;
  int tid = threadIdx.x;
  int s1 = eidx[b * 4 + 0], e1 = eidx[b * 4 + 1];
  int s2 = eidx[b * 4 + 2], e2 = eidx[b * 4 + 3];
  float c1 = (float)max(e1 - s1, 1);
  float c2 = (float)max(e2 - s2, 1);
  const float* xb = x + (size_t)b * SS * HH;
  float* tb = t_cat + (size_t)b * 3 * HH;
  for (int h = tid; h < HH; h += 256) {
    float v0 = xb[h];
    float a1 = 0.f, a2 = 0.f;
    for (int s = s1; s < e1; ++s) a1 += xb[(size_t)s * HH + h];
    for (int s = s2; s < e2; ++s) a2 += xb[(size_t)s * HH + h];
    tb[h]          = tanhf(v0);
    tb[HH + h]     = tanhf(a1 / c1);
    tb[2 * HH + h] = tanhf(a2 / c2);
  }
}

// ---------------- generic 64-row GEMM tile ----------------
// Computes C[0:64, j0:j0+64] (+= if useAtomic) = A[0:64, k0:kend] @ W[k0:kend, j0:j0+64]
// 256 threads as 16x16, each thread a 4x4 sub-tile.
__device__ __forceinline__ void gemm_tile_body(
    const float* __restrict__ A, int lda,
    const float* __restrict__ W, int ldw,
    const float* __restrict__ bias,
    float* __restrict__ C, int ldc,
    int k0, int kend, int j0, bool addBias, bool useAtomic) {
  __shared__ float As[64][33];  // +1 pad breaks bank conflicts on column reads
  __shared__ float Ws[32][64];
  int tid = threadIdx.x;
  int tx = tid & 15, ty = tid >> 4;
  float acc[4][4] = {{0.f}};
  for (int kb = k0; kb < kend; kb += 32) {
#pragma unroll
    for (int i = 0; i < 8; ++i) {
      int idx = tid + i * 256;
      As[idx >> 5][idx & 31] = A[(size_t)(idx >> 5) * lda + kb + (idx & 31)];
    }
#pragma unroll
    for (int i = 0; i < 8; ++i) {
      int idx = tid + i * 256;
      Ws[idx >> 6][idx & 63] = W[(size_t)(kb + (idx >> 6)) * ldw + j0 + (idx & 63)];
    }
    __syncthreads();
#pragma unroll
    for (int kk = 0; kk < 32; ++kk) {
      float a[4], w[4];
#pragma unroll
      for (int i = 0; i < 4; ++i) a[i] = As[ty * 4 + i][kk];
#pragma unroll
      for (int j = 0; j < 4; ++j) w[j] = Ws[kk][tx * 4 + j];
#pragma unroll
      for (int i = 0; i < 4; ++i)
#pragma unroll
        for (int j = 0; j < 4; ++j) acc[i][j] += a[i] * w[j];
    }
    __syncthreads();
  }
#pragma unroll
  for (int i = 0; i < 4; ++i) {
    int r = ty * 4 + i;
#pragma unroll
    for (int j = 0; j < 4; ++j) {
      int c = j0 + tx * 4 + j;
      float v = acc[i][j];
      if (addBias) v += bias[c];
      if (useAtomic) atomicAdd(&C[(size_t)r * ldc + c], v);
      else C[(size_t)r * ldc + c] = v;
    }
  }
}

// Block-diagonal stage: 3 branches (cls/subj/obj), blockIdx.z selects branch.
// grid: (16 j-tiles, KSPLIT, 3)
__global__ void gemm_bd_kernel(const float* __restrict__ t_cat,
                               const float* __restrict__ Wc, const float* __restrict__ bc,
                               const float* __restrict__ We1, const float* __restrict__ be1,
                               const float* __restrict__ We2, const float* __restrict__ be2,
                               float* __restrict__ h_cat, int Kchunk) {
  int z = blockIdx.z;
  const float* W = (z == 0) ? Wc : ((z == 1) ? We1 : We2);
  const float* bias = (z == 0) ? bc : ((z == 1) ? be1 : be2);
  const float* A = t_cat + z * HH;
  float* C = h_cat + z * HH;
  int k0 = blockIdx.y * Kchunk;
  gemm_tile_body(A, 3 * HH, W, HH, bias, C, 3 * HH,
                 k0, k0 + Kchunk, blockIdx.x * 64,
                 blockIdx.y == 0, true);
}

// Plain split-K GEMM: grid (N/64, KSPLIT)
__global__ void gemm_kernel(const float* __restrict__ A, int lda,
                            const float* __restrict__ W, int ldw,
                            const float* __restrict__ bias,
                            float* __restrict__ C, int ldc, int Kchunk) {
  int k0 = blockIdx.y * Kchunk;
  gemm_tile_body(A, lda, W, ldw, bias, C, ldc,
                 k0, k0 + Kchunk, blockIdx.x * 64,
                 blockIdx.y == 0, gridDim.y > 1);
}

// ---------------- final 1024 -> 15 ----------------
// 960 outputs, one thread each
__global__ void out_kernel(const float* __restrict__ h2,
                           const float* __restrict__ Wout,
                           const float* __restrict__ bout,
                           float* __restrict__ out) {
  int idx = blockIdx.x * blockDim.x + threadIdx.x;
  if (idx >= BB * LL) return;
  int b = idx / LL, l = idx % LL;
  const float* h = h2 + (size_t)b * HH;
  float acc = bout[l];
#pragma unroll 8
  for (int k = 0; k < HH; ++k) acc += h[k] * Wout[(size_t)k * LL + l];
  out[idx] = acc;
}

extern "C" void kernel_launch(void* const* d_in, const int* in_sizes, int n_in,
                              void* d_out, int out_size, void* d_ws, size_t ws_size,
                              hipStream_t stream) {
  const float* x     = (const float*)d_in[0];
  const int*   eidx  = (const int*)d_in[1];
  const float* W_cls = (const float*)d_in[2];
  const float* b_cls = (const float*)d_in[3];
  const float* W_e1  = (const float*)d_in[4];
  const float* b_e1  = (const float*)d_in[5];
  const float* W_e2  = (const float*)d_in[6];
  const float* b_e2  = (const float*)d_in[7];
  const float* W1    = (const float*)d_in[8];
  const float* b1    = (const float*)d_in[9];
  const float* W2    = (const float*)d_in[10];
  const float* b2    = (const float*)d_in[11];
  const float* Wout  = (const float*)d_in[12];
  const float* bout  = (const float*)d_in[13];
  float* out = (float*)d_out;

  float* ws    = (float*)d_ws;
  float* t_cat = ws;                          // 64*3072
  float* h_cat = t_cat + BB * 3 * HH;         // 64*3072
  float* h1    = h_cat + BB * 3 * HH;         // 64*1024
  float* h2    = h1 + BB * HH;                // 64*1024

  // zero the atomic-accumulated buffers (h_cat, h1, h2 are contiguous)
  hipMemsetAsync(h_cat, 0, (size_t)(BB * 3 * HH + BB * HH + BB * HH) * sizeof(float), stream);

  span_tanh_kernel<<<BB, 256, 0, stream>>>(x, eidx, t_cat);

  // stage 1: block-diag [64,3072] -> [64,3072]; K=1024 split 4 (Kchunk 256)
  gemm_bd_kernel<<<dim3(16, 4, 3), 256, 0, stream>>>(
      t_cat, W_cls, b_cls, W_e1, b_e1, W_e2, b_e2, h_cat, 256);

  // stage 2: [64,3072] @ [3072,1024]; K split 8 (Kchunk 384)
  gemm_kernel<<<dim3(16, 8, 1), 256, 0, stream>>>(h_cat, 3 * HH, W1, HH, b1, h1, HH, 384);

  // stage 3: [64,1024] @ [1024,1024]; K split 4 (Kchunk 256)
  gemm_kernel<<<dim3(16, 4, 1), 256, 0, stream>>>(h1, HH, W2, HH, b2, h2, HH, 256);

  // stage 4: [64,1024] @ [1024,15]
  out_kernel<<<dim3((BB * LL + 255) / 256), 256, 0, stream>>>(h2, Wout, bout, out);
}

// Round 2
// 726.371 us; speedup vs baseline: 1.1396x; 1.1396x over previous
//
#include <hip/hip_runtime.h>
#include <math.h>

#define BB 64
#define SS 2048
#define HH 1024
#define LL 15

// ---------------- span-mean + tanh + zero-init of downstream buffers ----------------
// grid: (64 b, 4 hchunk), 256 threads. Each block handles 256 h-values of one batch row.
// Also zeroes its slice of h_cat/h1/h2 (replaces a separate memset dispatch; the
// downstream GEMMs accumulate atomically into these).
__global__ void span_tanh_kernel(const float* __restrict__ x,
                                 const int* __restrict__ eidx,
                                 float* __restrict__ t_cat,
                                 float* __restrict__ h_cat,
                                 float* __restrict__ h1,
                                 float* __restrict__ h2) {
  int b = blockIdx.x;
  int hc = blockIdx.y;
  int tid = threadIdx.x;
  int h = hc * 256 + tid;

  // zero slices (harness poisons ws with 0xAA before every launch)
  {
    float* z = h_cat + (size_t)b * 3 * HH + hc * 768;
    for (int i = tid; i < 768; i += 256) z[i] = 0.f;
    h1[(size_t)b * HH + hc * 256 + tid] = 0.f;
    h2[(size_t)b * HH + hc * 256 + tid] = 0.f;
  }

  int s1 = eidx[b * 4 + 0], e1 = eidx[b * 4 + 1];
  int s2 = eidx[b * 4 + 2], e2 = eidx[b * 4 + 3];
  float c1 = (float)max(e1 - s1, 1);
  float c2 = (float)max(e2 - s2, 1);
  const float* xb = x + (size_t)b * SS * HH;
  float* tb = t_cat + (size_t)b * 3 * HH;

  float v0 = xb[h];
  float a1 = 0.f, a2 = 0.f;
  for (int s = s1; s < e1; ++s) a1 += xb[(size_t)s * HH + h];
  for (int s = s2; s < e2; ++s) a2 += xb[(size_t)s * HH + h];
  tb[h]          = tanhf(v0);
  tb[HH + h]     = tanhf(a1 / c1);
  tb[2 * HH + h] = tanhf(a2 / c2);
}

// ---------------- 64x64 GEMM tile, k-major LDS, register double-buffer ----------------
// C[0:64, j0:j0+64] += A[0:64, k0:kend] @ W[k0:kend, j0:j0+64]  (atomic accumulate)
// 256 threads as 16x16, each a 4x4 micro-tile. LDS stride 68 keeps float4 alignment
// (68*4=272 B, mult of 16) while breaking power-of-2 bank strides.
#define LSTR 68
__device__ __forceinline__ void gemm_tile_body(
    const float* __restrict__ A, int lda,
    const float* __restrict__ W, int ldw,
    const float* __restrict__ bias,
    float* __restrict__ C, int ldc,
    int k0, int kend, int j0, bool addBias) {
  __shared__ float As[32 * LSTR];  // [kk][row]
  __shared__ float Ws[32 * LSTR];  // [kk][col]
  int tid = threadIdx.x;
  int tx = tid & 15, ty = tid >> 4;

  // A-load assignment: idx = tid + i*256 -> row = idx&63, kq = idx>>6 (float4 over k)
  // W-load assignment: idx = tid + i*256 -> row = idx>>4,  cq = idx&15 (float4 over cols)
  float4 aReg[2], wReg[2];
  int aRow[2], aKq[2], wRow[2], wCq[2];
#pragma unroll
  for (int i = 0; i < 2; ++i) {
    int idx = tid + i * 256;
    aRow[i] = idx & 63; aKq[i] = idx >> 6;
    wRow[i] = idx >> 4; wCq[i] = idx & 15;
  }

  auto loadRegs = [&](int kb) {
#pragma unroll
    for (int i = 0; i < 2; ++i) {
      aReg[i] = *(const float4*)&A[(size_t)aRow[i] * lda + kb + 4 * aKq[i]];
      wReg[i] = *(const float4*)&W[(size_t)(kb + wRow[i]) * ldw + j0 + 4 * wCq[i]];
    }
  };

  float acc[4][4] = {{0.f}};
  loadRegs(k0);
  for (int kb = k0; kb < kend; kb += 32) {
    // stage regs -> LDS (k-major; A transposed during store)
#pragma unroll
    for (int i = 0; i < 2; ++i) {
      float av[4] = {aReg[i].x, aReg[i].y, aReg[i].z, aReg[i].w};
#pragma unroll
      for (int j = 0; j < 4; ++j) As[(4 * aKq[i] + j) * LSTR + aRow[i]] = av[j];
      *(float4*)&Ws[wRow[i] * LSTR + 4 * wCq[i]] = wReg[i];
    }
    __syncthreads();
    if (kb + 32 < kend) loadRegs(kb + 32);  // prefetch next k-block while computing
#pragma unroll
    for (int kk = 0; kk < 32; ++kk) {
      float4 a4 = *(const float4*)&As[kk * LSTR + ty * 4];
      float4 w4 = *(const float4*)&Ws[kk * LSTR + tx * 4];
      float a[4] = {a4.x, a4.y, a4.z, a4.w};
      float w[4] = {w4.x, w4.y, w4.z, w4.w};
#pragma unroll
      for (int i = 0; i < 4; ++i)
#pragma unroll
        for (int j = 0; j < 4; ++j) acc[i][j] += a[i] * w[j];
    }
    __syncthreads();
  }
#pragma unroll
  for (int i = 0; i < 4; ++i) {
    int r = ty * 4 + i;
#pragma unroll
    for (int j = 0; j < 4; ++j) {
      int c = j0 + tx * 4 + j;
      float v = acc[i][j];
      if (addBias) v += bias[c];
      atomicAdd(&C[(size_t)r * ldc + c], v);
    }
  }
}

// Block-diagonal stage: 3 branches (cls/subj/obj), blockIdx.z selects branch.
__global__ void gemm_bd_kernel(const float* __restrict__ t_cat,
                               const float* __restrict__ Wc, const float* __restrict__ bc,
                               const float* __restrict__ We1, const float* __restrict__ be1,
                               const float* __restrict__ We2, const float* __restrict__ be2,
                               float* __restrict__ h_cat, int Kchunk) {
  int z = blockIdx.z;
  const float* W = (z == 0) ? Wc : ((z == 1) ? We1 : We2);
  const float* bias = (z == 0) ? bc : ((z == 1) ? be1 : be2);
  const float* A = t_cat + z * HH;
  float* C = h_cat + z * HH;
  int k0 = blockIdx.y * Kchunk;
  gemm_tile_body(A, 3 * HH, W, HH, bias, C, 3 * HH,
                 k0, k0 + Kchunk, blockIdx.x * 64, blockIdx.y == 0);
}

// Plain split-K GEMM: grid (N/64, KSPLIT)
__global__ void gemm_kernel(const float* __restrict__ A, int lda,
                            const float* __restrict__ W, int ldw,
                            const float* __restrict__ bias,
                            float* __restrict__ C, int ldc, int Kchunk) {
  int k0 = blockIdx.y * Kchunk;
  gemm_tile_body(A, lda, W, ldw, bias, C, ldc,
                 k0, k0 + Kchunk, blockIdx.x * 64, blockIdx.y == 0);
}

// ---------------- final 1024 -> 15: one wave per output ----------------
// 960 outputs = 960 waves = 240 blocks of 256
__global__ void out_kernel(const float* __restrict__ h2,
                           const float* __restrict__ Wout,
                           const float* __restrict__ bout,
                           float* __restrict__ out) {
  int tid = threadIdx.x;
  int lane = tid & 63;
  int idx = blockIdx.x * 4 + (tid >> 6);
  int b = idx / LL, l = idx % LL;
  const float* h = h2 + (size_t)b * HH;
  float acc = 0.f;
#pragma unroll
  for (int w = 0; w < 4; ++w) {
    int k0 = (w * 64 + lane) * 4;
    float4 h4 = *(const float4*)&h[k0];
    acc += h4.x * Wout[(size_t)(k0 + 0) * LL + l];
    acc += h4.y * Wout[(size_t)(k0 + 1) * LL + l];
    acc += h4.z * Wout[(size_t)(k0 + 2) * LL + l];
    acc += h4.w * Wout[(size_t)(k0 + 3) * LL + l];
  }
#pragma unroll
  for (int off = 32; off > 0; off >>= 1) acc += __shfl_down(acc, off, 64);
  if (lane == 0) out[idx] = acc + bout[l];
}

extern "C" void kernel_launch(void* const* d_in, const int* in_sizes, int n_in,
                              void* d_out, int out_size, void* d_ws, size_t ws_size,
                              hipStream_t stream) {
  const float* x     = (const float*)d_in[0];
  const int*   eidx  = (const int*)d_in[1];
  const float* W_cls = (const float*)d_in[2];
  const float* b_cls = (const float*)d_in[3];
  const float* W_e1  = (const float*)d_in[4];
  const float* b_e1  = (const float*)d_in[5];
  const float* W_e2  = (const float*)d_in[6];
  const float* b_e2  = (const float*)d_in[7];
  const float* W1    = (const float*)d_in[8];
  const float* b1    = (const float*)d_in[9];
  const float* W2    = (const float*)d_in[10];
  const float* b2    = (const float*)d_in[11];
  const float* Wout  = (const float*)d_in[12];
  const float* bout  = (const float*)d_in[13];
  float* out = (float*)d_out;

  float* ws    = (float*)d_ws;
  float* t_cat = ws;                          // 64*3072
  float* h_cat = t_cat + BB * 3 * HH;         // 64*3072 (atomic-accumulated)
  float* h1    = h_cat + BB * 3 * HH;         // 64*1024 (atomic-accumulated)
  float* h2    = h1 + BB * HH;                // 64*1024 (atomic-accumulated)

  // K1: span means + tanh, plus zero-init of h_cat/h1/h2 (256 blocks)
  span_tanh_kernel<<<dim3(BB, 4), 256, 0, stream>>>(x, eidx, t_cat, h_cat, h1, h2);

  // K2: block-diag [64,3072] -> [64,3072]; K=1024, KS=4 (Kchunk 256) -> 192 blocks
  gemm_bd_kernel<<<dim3(16, 4, 3), 256, 0, stream>>>(
      t_cat, W_cls, b_cls, W_e1, b_e1, W_e2, b_e2, h_cat, 256);

  // K3: [64,3072] @ [3072,1024]; K=3072, KS=12 (Kchunk 256) -> 192 blocks
  gemm_kernel<<<dim3(16, 12, 1), 256, 0, stream>>>(h_cat, 3 * HH, W1, HH, b1, h1, HH, 256);

  // K4: [64,1024] @ [1024,1024]; K=1024, KS=8 (Kchunk 128) -> 128 blocks
  gemm_kernel<<<dim3(16, 8, 1), 256, 0, stream>>>(h1, HH, W2, HH, b2, h2, HH, 128);

  // K5: [64,1024] @ [1024,15]; wave-per-output
  out_kernel<<<dim3(240), 256, 0, stream>>>(h2, Wout, bout, out);
}